// Round 9
// baseline (336.919 us; speedup 1.0000x reference)
//
#include <hip/hip_runtime.h>
#include <hip/hip_bf16.h>

// Transformer-XL block: BS=2, QS=KS=2048, H=1024, NH=16, HD=64
// score[b,q,k,n] = ((q+rw)·K[k] + (q+rr)·r[2047-(q-k)]) / 8 for k<=q, -inf else.
// R9: attn QBLK=128 / 8 waves (staging+barriers per unit work halve; LDS 77.8KB
//     -> 2 blocks/CU = 50% occ ceiling; ring 256 slots, jb=1920-q0+k0,
//     t0w=112-16wv); R-GEMM merged into QKV GEMM (bsel=3).

typedef _Float16 f16;
typedef __attribute__((ext_vector_type(8))) _Float16 f16x8;
typedef __attribute__((ext_vector_type(4))) float f32x4;

__device__ __forceinline__ void gload16(const f16* g, f16* l) {
  __builtin_amdgcn_global_load_lds((__attribute__((address_space(1))) void*)(g),
                                   (__attribute__((address_space(3))) void*)(l), 16, 0, 0);
}

// ---------------- fused cast f32 -> f16 (x and pos_emb) ----------------
__global__ __launch_bounds__(256) void cast2_kernel(const float* __restrict__ a,
                                                    f16* __restrict__ ao, int na4,
                                                    const float* __restrict__ b,
                                                    f16* __restrict__ bo, int nb4) {
  int i = blockIdx.x * 256 + threadIdx.x;
  const float* src;
  f16* dst;
  int j;
  if (i < na4) { src = a; dst = ao; j = i; }
  else { j = i - na4; if (j >= nb4) return; src = b; dst = bo; }
  f32x4 v = *(const f32x4*)&src[j * 4];
  f16 o0 = (f16)v[0], o1 = (f16)v[1], o2 = (f16)v[2], o3 = (f16)v[3];
  f16* p = &dst[j * 4];
  p[0] = o0; p[1] = o1; p[2] = o2; p[3] = o3;
}

// ---------------- W[k][n] f32 -> WT[n][k] f16, all 5 weights in one launch ----------------
__global__ __launch_bounds__(256) void wtrans5_kernel(
    const float* __restrict__ W0, const float* __restrict__ W1, const float* __restrict__ W2,
    const float* __restrict__ W3, const float* __restrict__ W4,
    f16* __restrict__ T0, f16* __restrict__ T1, f16* __restrict__ T2,
    f16* __restrict__ T3, f16* __restrict__ T4) {
  __shared__ float tile[32][33];
  const float* W;
  f16* WT;
  switch (blockIdx.z) {
    case 0: W = W0; WT = T0; break;
    case 1: W = W1; WT = T1; break;
    case 2: W = W2; WT = T2; break;
    case 3: W = W3; WT = T3; break;
    default: W = W4; WT = T4; break;
  }
  int k0 = blockIdx.x * 32, n0 = blockIdx.y * 32;
  int tx = threadIdx.x, ty = threadIdx.y;
#pragma unroll
  for (int i = 0; i < 4; ++i)
    tile[ty + i * 8][tx] = W[(size_t)(k0 + ty + i * 8) * 1024 + n0 + tx];
  __syncthreads();
#pragma unroll
  for (int i = 0; i < 4; ++i)
    WT[(size_t)(n0 + ty + i * 8) * 1024 + k0 + tx] = (f16)tile[tx][ty + i * 8];
}

// ---------------- fused QKV+R GEMM: 128x128 tile, swizzled gload_lds staging ----------------
// bsel = blockIdx.x>>3: 0=Q(+biases), 1=K, 2=V(transpose epilogue), 3=R (M=2048).
// LDS: physical 16B-chunk p of row r holds logical chunk p ^ (r&7).
__global__ __launch_bounds__(256) void gemm_qkvr(
    const f16* __restrict__ A, const f16* __restrict__ pb,
    const f16* __restrict__ Bq, const f16* __restrict__ Bk,
    const f16* __restrict__ Bv, const f16* __restrict__ Br,
    f16* __restrict__ Qw, f16* __restrict__ Qr,
    f16* __restrict__ Kb, f16* __restrict__ VTb, f16* __restrict__ Rb,
    const float* __restrict__ rw, const float* __restrict__ rr) {
  __shared__ f16 sm[17408];  // As[128*64] | Bs[128*64]; union with T[128][136]
  f16* As = sm;
  f16* Bs = sm + 8192;
  const int bsel = blockIdx.x >> 3;
  if (bsel == 3 && blockIdx.y >= 16) return;  // R has M=2048 only
  const f16* Ap = (bsel == 3) ? pb : A;
  const f16* Bw = bsel == 0 ? Bq : (bsel == 1 ? Bk : (bsel == 2 ? Bv : Br));
  const int n0 = (blockIdx.x & 7) * 128, m0 = blockIdx.y * 128;
  const int tid = threadIdx.x, lane = tid & 63, wv = tid >> 6;
  const int wm = wv >> 1, wn = wv & 1, lg = lane >> 4, ln = lane & 15;
  const int srow = lane >> 3;                 // row within 8-row chunk
  const int sw = (lane & 7) ^ srow;           // pre-swizzled source 16B-chunk
  f32x4 acc[4][4] = {};

  for (int kt = 0; kt < 16; ++kt) {
    __syncthreads();
#pragma unroll
    for (int i = 0; i < 4; ++i) {
      int c = wv * 4 + i;  // 1KB chunk: rows 8c..8c+7
      gload16(Ap + (size_t)(m0 + c * 8 + srow) * 1024 + kt * 64 + sw * 8, &As[c * 512]);
      gload16(Bw + (size_t)(n0 + c * 8 + srow) * 1024 + kt * 64 + sw * 8, &Bs[c * 512]);
    }
    __syncthreads();
#pragma unroll
    for (int ks = 0; ks < 2; ++ks) {
      f16x8 af[4], bfr[4];
#pragma unroll
      for (int mi = 0; mi < 4; ++mi)
        af[mi] = *(const f16x8*)&As[(wm * 64 + mi * 16 + ln) * 64 +
                                    (((ks * 4 + lg) ^ (ln & 7)) * 8)];
#pragma unroll
      for (int ni = 0; ni < 4; ++ni)
        bfr[ni] = *(const f16x8*)&Bs[(wn * 64 + ni * 16 + ln) * 64 +
                                     (((ks * 4 + lg) ^ (ln & 7)) * 8)];
#pragma unroll
      for (int mi = 0; mi < 4; ++mi)
#pragma unroll
        for (int ni = 0; ni < 4; ++ni)
          acc[mi][ni] = __builtin_amdgcn_mfma_f32_16x16x32_f16(af[mi], bfr[ni],
                                                               acc[mi][ni], 0, 0, 0);
    }
  }

  if (bsel == 2) {  // V: transpose epilogue -> VT[b,n,d,s]
    __syncthreads();
    f16* T = sm;  // [128][136]
#pragma unroll
    for (int mi = 0; mi < 4; ++mi)
#pragma unroll
      for (int ni = 0; ni < 4; ++ni)
#pragma unroll
        for (int r = 0; r < 4; ++r) {
          int ml = wm * 64 + mi * 16 + 4 * lg + r;
          int cl = wn * 64 + ni * 16 + ln;
          T[cl * 136 + ml] = (f16)acc[mi][ni][r];
        }
    __syncthreads();
    int cl = tid >> 1, mb = (tid & 1) * 64;
    int gc = n0 + cl, gm = m0 + mb;
    int hh = gc >> 6, dd = gc & 63, bb = gm >> 11, ss = gm & 2047;
    f16* dst = VTb + ((size_t)(bb * 16 + hh) * 64 + dd) * 2048 + ss;
    const f16* srcT = &T[cl * 136 + mb];
#pragma unroll
    for (int i = 0; i < 8; ++i) *(f16x8*)&dst[i * 8] = *(const f16x8*)&srcT[i * 8];
  } else {
#pragma unroll
    for (int mi = 0; mi < 4; ++mi)
#pragma unroll
      for (int ni = 0; ni < 4; ++ni)
#pragma unroll
        for (int r = 0; r < 4; ++r) {
          int m = m0 + wm * 64 + mi * 16 + 4 * lg + r;
          int c = n0 + wn * 64 + ni * 16 + ln;
          float v = acc[mi][ni][r];
          size_t off = (size_t)m * 1024 + c;
          if (bsel == 0) {
            Qw[off] = (f16)(v + rw[c]);
            Qr[off] = (f16)(v + rr[c]);
          } else if (bsel == 1) {
            Kb[off] = (f16)v;
          } else {
            Rb[off] = (f16)v;
          }
        }
  }
}

// ---------------- BM=64 GEMM (swizzled gload_lds): O (+residual f32) ----------------
__global__ __launch_bounds__(256) void gemm_o(
    const f16* __restrict__ A, const f16* __restrict__ Bw,
    float* __restrict__ fout, const float* __restrict__ xres) {
  __shared__ f16 As[4096];   // [64][64] swizzled
  __shared__ f16 Bs[8192];   // [128][64] swizzled
  const int tid = threadIdx.x, lane = tid & 63, wv = tid >> 6;
  const int wm = wv >> 1, wn = wv & 1, lg = lane >> 4, ln = lane & 15;
  const int m0 = blockIdx.y * 64, n0 = blockIdx.x * 128;
  const int srow = lane >> 3;
  const int sw = (lane & 7) ^ srow;
  f32x4 acc[2][4] = {};

  for (int kt = 0; kt < 16; ++kt) {
    __syncthreads();
#pragma unroll
    for (int i = 0; i < 2; ++i) {
      int c = wv * 2 + i;
      gload16(A + (size_t)(m0 + c * 8 + srow) * 1024 + kt * 64 + sw * 8, &As[c * 512]);
    }
#pragma unroll
    for (int i = 0; i < 4; ++i) {
      int c = wv * 4 + i;
      gload16(Bw + (size_t)(n0 + c * 8 + srow) * 1024 + kt * 64 + sw * 8, &Bs[c * 512]);
    }
    __syncthreads();
#pragma unroll
    for (int ks = 0; ks < 2; ++ks) {
      f16x8 af[2], bfr[4];
#pragma unroll
      for (int mi = 0; mi < 2; ++mi)
        af[mi] = *(const f16x8*)&As[(wm * 32 + mi * 16 + ln) * 64 +
                                    (((ks * 4 + lg) ^ (ln & 7)) * 8)];
#pragma unroll
      for (int ni = 0; ni < 4; ++ni)
        bfr[ni] = *(const f16x8*)&Bs[(wn * 64 + ni * 16 + ln) * 64 +
                                     (((ks * 4 + lg) ^ (ln & 7)) * 8)];
#pragma unroll
      for (int mi = 0; mi < 2; ++mi)
#pragma unroll
        for (int ni = 0; ni < 4; ++ni)
          acc[mi][ni] = __builtin_amdgcn_mfma_f32_16x16x32_f16(af[mi], bfr[ni],
                                                               acc[mi][ni], 0, 0, 0);
    }
  }
#pragma unroll
  for (int mi = 0; mi < 2; ++mi)
#pragma unroll
    for (int ni = 0; ni < 4; ++ni)
#pragma unroll
      for (int r = 0; r < 4; ++r) {
        int m = m0 + wm * 32 + mi * 16 + 4 * lg + r;
        int c = n0 + wn * 64 + ni * 16 + ln;
        size_t off = (size_t)m * 1024 + c;
        fout[off] = acc[mi][ni][r] + xres[off];
      }
}

// chunk id c (0..39) -> (qt, ci) for QBLK=128. k-tiles per qt = 2qt+2.
// qt 0..3: 1 chunk; 4..7: 2; 8..11: 3; 12..15: 4.
__device__ __forceinline__ void chunk_map(int c, int& qt, int& ci) {
  if (c < 4) { qt = c; ci = 0; }
  else if (c < 12) { qt = 4 + ((c - 4) >> 1); ci = (c - 4) & 1; }
  else if (c < 24) { int d = c - 12; qt = 8 + d / 3; ci = d % 3; }
  else { int d = c - 24; qt = 12 + (d >> 2); ci = d & 3; }
}

// ---------------- split-K flash attention: QBLK=128, 8 waves ----------------
// Wave wv owns q-rows [16wv,16wv+16). Ring Rl: slot j&255 holds r[j].
// Window per tile: t in [0,190], j = jb+t, jb = 1920-q0+k0; per-wave 80-wide
// slice t0w = 112-16wv. Gather u = ki-ql+15 in [0,78].
__global__ __launch_bounds__(512) void attn_chunk(
    const f16* __restrict__ Qw, const f16* __restrict__ Qr,
    const f16* __restrict__ Kb, const f16* __restrict__ VT,
    const f16* __restrict__ Rb, f16* __restrict__ attb,
    f16* __restrict__ Opart, float* __restrict__ Mlp) {
  constexpr int LD = 72;
  constexpr int MW = 88;
  __shared__ f16 Kl[64 * LD];    // [key][d]
  __shared__ f16 Vl[64 * LD];    // [d][key]
  __shared__ f16 Rl[256 * LD];   // ring: slot j&255 holds r[j] (0 beyond 2047)
  __shared__ f16 Sl[128 * MW];   // wave-private union: M-park / P / out-bounce

  int qt, ci;
  chunk_map(39 - blockIdx.x, qt, ci);   // big chunks dispatch first
  const int c = 39 - blockIdx.x;
  const int h = blockIdx.y, b = blockIdx.z;
  const int q0 = qt * 128;
  const int kts = ci * 8;
  const int kte = min(kts + 7, 2 * qt + 1);
  const int tid = threadIdx.x, lane = tid & 63, wv = tid >> 6;
  const int lg = lane >> 4, ln = lane & 15;

  const size_t qoff = ((size_t)(b * 2048 + q0 + wv * 16 + ln) * 16 + h) * 64 + 8 * lg;
  f16x8 aqw[2], aqr[2];
  aqw[0] = *(const f16x8*)&Qw[qoff];
  aqw[1] = *(const f16x8*)&Qw[qoff + 32];
  aqr[0] = *(const f16x8*)&Qr[qoff];
  aqr[1] = *(const f16x8*)&Qr[qoff + 32];

  f32x4 oacc[4] = {};
  float mrun[4] = {-1e30f, -1e30f, -1e30f, -1e30f};
  float lrun[4] = {0.f, 0.f, 0.f, 0.f};

  const int r8 = tid >> 3, c8 = (tid & 7) * 8;  // staging map: 64 rows x 64 cols
  const int t0w = 112 - 16 * wv;                // wave-local BD window base

  f16x8 pk, pv, prn;  // prefetch registers
  auto load_kv = [&](int kt) {
    const int k0 = kt * 64;
    pk = *(const f16x8*)&Kb[((size_t)(b * 2048 + k0 + r8) * 16 + h) * 64 + c8];
    pv = *(const f16x8*)&VT[((size_t)(b * 16 + h) * 64 + r8) * 2048 + k0 + c8];
  };
  auto load_r = [&](int jbcur) {  // 64 new rows for next tile: j = jb+191+r8
    const int j = jbcur + 191 + r8;
    if (j < 2048) prn = *(const f16x8*)&Rb[((size_t)j * 16 + h) * 64 + c8];
    else { f16x8 z = {}; prn = z; }
  };
  auto write_kv = [&]() {
    *(f16x8*)&Kl[r8 * LD + c8] = pk;
    *(f16x8*)&Vl[r8 * LD + c8] = pv;
  };
  auto write_r = [&](int jbcur) {
    const int slot = (jbcur + 191 + r8) & 255;
    *(f16x8*)&Rl[slot * LD + c8] = prn;
  };

  const int jb0 = 1920 - q0 + kts * 64;
  load_kv(kts);
  write_kv();
#pragma unroll
  for (int pass = 0; pass < 3; ++pass) {  // initial window: rows jb0..jb0+191
    const int t = pass * 64 + r8;
    const int j = jb0 + t;
    const int slot = j & 255;
    if (j < 2048)
      *(f16x8*)&Rl[slot * LD + c8] = *(const f16x8*)&Rb[((size_t)j * 16 + h) * 64 + c8];
    else { f16x8 z = {}; *(f16x8*)&Rl[slot * LD + c8] = z; }
  }
  __syncthreads();

  for (int kt = kts; kt <= kte; ++kt) {
    const int k0 = kt * 64;
    const int jb = 1920 - q0 + k0;
    if (kt < kte) {  // VMEM latency hides under compute below
      load_kv(kt + 1);
      load_r(jb);
    }

    // AC = (Q+rw) @ K^T
    f32x4 sc[4] = {};
#pragma unroll
    for (int ks = 0; ks < 2; ++ks)
#pragma unroll
      for (int ni = 0; ni < 4; ++ni) {
        f16x8 kf = *(const f16x8*)&Kl[(ni * 16 + ln) * LD + ks * 32 + 8 * lg];
        sc[ni] = __builtin_amdgcn_mfma_f32_16x16x32_f16(aqw[ks], kf, sc[ni], 0, 0, 0);
      }

    // BD wave-local 80-wide window via ring slots
    f32x4 mw[5] = {};
#pragma unroll
    for (int ks = 0; ks < 2; ++ks)
#pragma unroll
      for (int nj = 0; nj < 5; ++nj) {
        const int slot = (jb + t0w + nj * 16 + ln) & 255;
        f16x8 rf = *(const f16x8*)&Rl[slot * LD + ks * 32 + 8 * lg];
        mw[nj] = __builtin_amdgcn_mfma_f32_16x16x32_f16(aqr[ks], rf, mw[nj], 0, 0, 0);
      }

    // park M (wave-private rows), shear-gather BD[ql,ki] = M[ql, ki-ql+15]
#pragma unroll
    for (int nj = 0; nj < 5; ++nj)
#pragma unroll
      for (int r = 0; r < 4; ++r)
        Sl[(wv * 16 + 4 * lg + r) * MW + nj * 16 + ln] = (f16)mw[nj][r];

#pragma unroll
    for (int ni = 0; ni < 4; ++ni)
#pragma unroll
      for (int r = 0; r < 4; ++r) {
        int ql = 4 * lg + r;
        int ki = ni * 16 + ln;
        float bd = (float)Sl[(wv * 16 + ql) * MW + ki - ql + 15];
        float s = (sc[ni][r] + bd) * 0.125f;
        if (k0 + ki > q0 + wv * 16 + ql) s = -1e30f;  // strict causal
        sc[ni][r] = s;
      }

    // online softmax over 16-lane row groups
#pragma unroll
    for (int r = 0; r < 4; ++r) {
      float mx = sc[0][r];
#pragma unroll
      for (int ni = 1; ni < 4; ++ni) mx = fmaxf(mx, sc[ni][r]);
#pragma unroll
      for (int off = 1; off < 16; off <<= 1) mx = fmaxf(mx, __shfl_xor(mx, off, 16));
      float mnew = fmaxf(mrun[r], mx);
      float corr = __expf(mrun[r] - mnew);
      mrun[r] = mnew;
      float rs = 0.f;
#pragma unroll
      for (int ni = 0; ni < 4; ++ni) {
        float p = __expf(sc[ni][r] - mnew);
        sc[ni][r] = p;
        rs += p;
      }
#pragma unroll
      for (int off = 1; off < 16; off <<= 1) rs += __shfl_xor(rs, off, 16);
      lrun[r] = lrun[r] * corr + rs;
#pragma unroll
      for (int ni = 0; ni < 4; ++ni) oacc[ni][r] *= corr;
    }

    // P park (wave-private rows), PV from Vl
#pragma unroll
    for (int ni = 0; ni < 4; ++ni)
#pragma unroll
      for (int r = 0; r < 4; ++r)
        Sl[(wv * 16 + 4 * lg + r) * MW + ni * 16 + ln] = (f16)sc[ni][r];

#pragma unroll
    for (int ks = 0; ks < 2; ++ks) {
      f16x8 pf = *(const f16x8*)&Sl[(wv * 16 + ln) * MW + ks * 32 + 8 * lg];
#pragma unroll
      for (int ni = 0; ni < 4; ++ni) {
        f16x8 vf = *(const f16x8*)&Vl[(ni * 16 + ln) * LD + ks * 32 + 8 * lg];
        oacc[ni] = __builtin_amdgcn_mfma_f32_16x16x32_f16(pf, vf, oacc[ni], 0, 0, 0);
      }
    }

    __syncthreads();  // all waves done reading LDS of this tile
    if (kt < kte) {
      write_kv();
      write_r(jb);
      __syncthreads();
    }
  }

  if (qt < 4) {
    // single chunk: normalize, bounce via wave-private rows, store final
#pragma unroll
    for (int ni = 0; ni < 4; ++ni)
#pragma unroll
      for (int r = 0; r < 4; ++r)
        Sl[(wv * 16 + 4 * lg + r) * MW + ni * 16 + ln] = (f16)(oacc[ni][r] / lrun[r]);
#pragma unroll
    for (int i = 0; i < 2; ++i) {
      int row = wv * 16 + i * 8 + (lane >> 3);
      int col = (lane & 7) * 8;
      *(f16x8*)&attb[((size_t)(b * 2048 + q0 + row) * 16 + h) * 64 + col] =
          *(const f16x8*)&Sl[row * MW + col];
    }
  } else {
    const size_t pidx = (size_t)(b * 16 + h) * 40 + c;
#pragma unroll
    for (int ni = 0; ni < 4; ++ni)
#pragma unroll
      for (int r = 0; r < 4; ++r)
        Sl[(wv * 16 + 4 * lg + r) * MW + ni * 16 + ln] = (f16)oacc[ni][r];
    if (ln == 0) {
#pragma unroll
      for (int r = 0; r < 4; ++r) {
        int row = wv * 16 + 4 * lg + r;
        Mlp[pidx * 256 + row] = mrun[r];
        Mlp[pidx * 256 + 128 + row] = lrun[r];
      }
    }
#pragma unroll
    for (int i = 0; i < 2; ++i) {
      int row = wv * 16 + i * 8 + (lane >> 3);
      int col = (lane & 7) * 8;
      *(f16x8*)&Opart[pidx * 8192 + row * 64 + col] = *(const f16x8*)&Sl[row * MW + col];
    }
  }
}

// ---------------- combine partials for qt >= 4 ----------------
__global__ __launch_bounds__(256) void combine_kernel(
    const f16* __restrict__ Opart, const float* __restrict__ Mlp,
    f16* __restrict__ attb) {
  const int qt = 4 + blockIdx.x, h = blockIdx.y, b = blockIdx.z;
  const int nc = (2 * qt + 9) >> 3;  // ceil((2qt+2)/8), 2..4
  int cbase;
  if (qt < 8) cbase = 4 + 2 * (qt - 4);
  else if (qt < 12) cbase = 12 + 3 * (qt - 8);
  else cbase = 24 + 4 * (qt - 12);
  const int tid = threadIdx.x;
  const size_t pbase = (size_t)(b * 16 + h) * 40 + cbase;

#pragma unroll
  for (int half = 0; half < 2; ++half) {
    const int row = half * 64 + (tid >> 2);
    const int d0 = (tid & 3) * 16;
    float m[4], l[4], w[4];
    float M = -1e30f;
#pragma unroll
    for (int i = 0; i < 4; ++i)
      if (i < nc) {
        m[i] = Mlp[(pbase + i) * 256 + row];
        l[i] = Mlp[(pbase + i) * 256 + 128 + row];
        M = fmaxf(M, m[i]);
      }
    float wsum = 0.f;
#pragma unroll
    for (int i = 0; i < 4; ++i)
      if (i < nc) {
        w[i] = __expf(m[i] - M);
        wsum += w[i] * l[i];
      }
    float o[16] = {};
#pragma unroll
    for (int i = 0; i < 4; ++i)
      if (i < nc) {
        const f16* src = &Opart[(pbase + i) * 8192 + row * 64 + d0];
        f16x8 v0 = *(const f16x8*)&src[0];
        f16x8 v1 = *(const f16x8*)&src[8];
#pragma unroll
        for (int j = 0; j < 8; ++j) {
          o[j] += w[i] * (float)v0[j];
          o[8 + j] += w[i] * (float)v1[j];
        }
      }
    float inv = 1.f / wsum;
    f16x8 r0, r1;
#pragma unroll
    for (int j = 0; j < 8; ++j) {
      r0[j] = (f16)(o[j] * inv);
      r1[j] = (f16)(o[8 + j] * inv);
    }
    f16* dst = &attb[((size_t)(b * 2048 + qt * 128 + row) * 16 + h) * 64 + d0];
    *(f16x8*)&dst[0] = r0;
    *(f16x8*)&dst[8] = r1;
  }
}

// ---------------- LayerNorm over last dim (1024), f32 out ----------------
__global__ __launch_bounds__(256) void ln_kernel(const float* __restrict__ pre,
                                                 const float* __restrict__ gamma,
                                                 const float* __restrict__ beta,
                                                 float* __restrict__ out) {
  __shared__ float red[8];
  const int row = blockIdx.x, t = threadIdx.x;
  f32x4 v = *(const f32x4*)&pre[(size_t)row * 1024 + t * 4];
  float s = v[0] + v[1] + v[2] + v[3];
  float s2 = v[0] * v[0] + v[1] * v[1] + v[2] * v[2] + v[3] * v[3];
#pragma unroll
  for (int off = 1; off < 64; off <<= 1) {
    s += __shfl_xor(s, off, 64);
    s2 += __shfl_xor(s2, off, 64);
  }
  if ((t & 63) == 0) {
    red[t >> 6] = s;
    red[(t >> 6) + 4] = s2;
  }
  __syncthreads();
  s = red[0] + red[1] + red[2] + red[3];
  s2 = red[4] + red[5] + red[6] + red[7];
  float mean = s * (1.f / 1024.f);
  float var = s2 * (1.f / 1024.f) - mean * mean;
  float rcp = rsqrtf(var + 1e-5f);
  f32x4 g = *(const f32x4*)&gamma[t * 4];
  f32x4 be = *(const f32x4*)&beta[t * 4];
  f32x4 o;
#pragma unroll
  for (int j = 0; j < 4; ++j) o[j] = (v[j] - mean) * rcp * g[j] + be[j];
  *(f32x4*)&out[(size_t)row * 1024 + t * 4] = o;
}

extern "C" void kernel_launch(void* const* d_in, const int* in_sizes, int n_in,
                              void* d_out, int out_size, void* d_ws, size_t ws_size,
                              hipStream_t stream) {
  const float* x = (const float*)d_in[0];
  const float* pe = (const float*)d_in[2];
  const float* rr = (const float*)d_in[3];
  const float* rw = (const float*)d_in[4];
  const float* Wq = (const float*)d_in[5];
  const float* Wk = (const float*)d_in[6];
  const float* Wv = (const float*)d_in[7];
  const float* Wr = (const float*)d_in[8];
  const float* Wo = (const float*)d_in[9];
  const float* gamma = (const float*)d_in[10];
  const float* beta = (const float*)d_in[11];
  float* out = (float*)d_out;

  char* w = (char*)d_ws;
  auto alloc = [&](size_t bytes) {
    char* p = w;
    w += (bytes + 255) & ~(size_t)255;
    return p;
  };
  float* preln = (float*)alloc(4096ull * 1024 * 4);
  f16* xb = (f16*)alloc(4096ull * 1024 * 2);
  f16* pb = (f16*)alloc(2048ull * 1024 * 2);
  f16* WTq = (f16*)alloc(1024ull * 1024 * 2);
  f16* WTk = (f16*)alloc(1024ull * 1024 * 2);
  f16* WTv = (f16*)alloc(1024ull * 1024 * 2);
  f16* WTr = (f16*)alloc(1024ull * 1024 * 2);
  f16* WTo = (f16*)alloc(1024ull * 1024 * 2);
  f16* Qw = (f16*)alloc(4096ull * 1024 * 2);
  f16* Qr = (f16*)alloc(4096ull * 1024 * 2);
  f16* Kb = (f16*)alloc(4096ull * 1024 * 2);
  f16* VTb = (f16*)alloc(4096ull * 1024 * 2);
  f16* Rb = (f16*)alloc(2048ull * 1024 * 2);
  f16* attb = (f16*)alloc(4096ull * 1024 * 2);
  f16* Opart = (f16*)alloc(2ull * 16 * 40 * 8192 * 2);  // 21 MB unnormalized O~
  float* Mlp = (float*)alloc(2ull * 16 * 40 * 256 * 4); // 1.3 MB m/l

  cast2_kernel<<<6144, 256, 0, stream>>>(x, xb, 4096 * 1024 / 4, pe, pb, 2048 * 1024 / 4);
  wtrans5_kernel<<<dim3(32, 32, 5), dim3(32, 8), 0, stream>>>(Wq, Wk, Wv, Wr, Wo,
                                                              WTq, WTk, WTv, WTr, WTo);

  gemm_qkvr<<<dim3(32, 32), 256, 0, stream>>>(xb, pb, WTq, WTk, WTv, WTr,
                                              Qw, Qr, Kb, VTb, Rb, rw, rr);

  attn_chunk<<<dim3(40, 16, 2), 512, 0, stream>>>(Qw, Qr, Kb, VTb, Rb, attb, Opart, Mlp);
  combine_kernel<<<dim3(12, 16, 2), 256, 0, stream>>>(Opart, Mlp, attb);

  gemm_o<<<dim3(8, 64), 256, 0, stream>>>(attb, WTo, preln, x);
  ln_kernel<<<4096, 256, 0, stream>>>(preln, gamma, beta, out);
}

// Round 10
// 313.781 us; speedup vs baseline: 1.0737x; 1.0737x over previous
//
#include <hip/hip_runtime.h>
#include <hip/hip_bf16.h>

// Transformer-XL block: BS=2, QS=KS=2048, H=1024, NH=16, HD=64
// score[b,q,k,n] = ((q+rw)·K[k] + (q+rr)·r[2047-(q-k)]) / 8 for k<=q, -inf else.
// R10: attn reverted to R8 structure (QBLK=64, 4 waves, ring R) + descending
//      chunk dispatch; GEMMs get XCD-chunked swizzle + merged 1D grids;
//      cast+wtrans merged into one prep kernel (8 -> 6 launches).

typedef _Float16 f16;
typedef __attribute__((ext_vector_type(8))) _Float16 f16x8;
typedef __attribute__((ext_vector_type(4))) float f32x4;

__device__ __forceinline__ void gload16(const f16* g, f16* l) {
  __builtin_amdgcn_global_load_lds((__attribute__((address_space(1))) void*)(g),
                                   (__attribute__((address_space(3))) void*)(l), 16, 0, 0);
}

// ---------------- prep: cast x/pos_emb to f16 + transpose 5 weights ----------------
__global__ __launch_bounds__(256) void prep_kernel(
    const float* __restrict__ x, f16* __restrict__ xb,
    const float* __restrict__ pe, f16* __restrict__ pb,
    const float* __restrict__ W0, const float* __restrict__ W1,
    const float* __restrict__ W2, const float* __restrict__ W3,
    const float* __restrict__ W4,
    f16* __restrict__ T0, f16* __restrict__ T1, f16* __restrict__ T2,
    f16* __restrict__ T3, f16* __restrict__ T4) {
  __shared__ float tile[32][33];
  const int id = blockIdx.x, tid = threadIdx.x;
  if (id < 6144) {  // cast: x is 1M f32x4, pe is 512K f32x4
    int i = id * 256 + tid;
    const float* src;
    f16* dst;
    int j;
    if (i < 1048576) { src = x; dst = xb; j = i; }
    else { j = i - 1048576; src = pe; dst = pb; }
    f32x4 v = *(const f32x4*)&src[(size_t)j * 4];
    f16* p = &dst[(size_t)j * 4];
    p[0] = (f16)v[0]; p[1] = (f16)v[1]; p[2] = (f16)v[2]; p[3] = (f16)v[3];
  } else {  // wtrans: 5 x 1024 blocks of 32x32 tiles
    const int wid = id - 6144;
    const int wsel = wid >> 10, rem = wid & 1023;
    const float* W;
    f16* WT;
    switch (wsel) {
      case 0: W = W0; WT = T0; break;
      case 1: W = W1; WT = T1; break;
      case 2: W = W2; WT = T2; break;
      case 3: W = W3; WT = T3; break;
      default: W = W4; WT = T4; break;
    }
    const int k0 = (rem >> 5) * 32, n0 = (rem & 31) * 32;
    const int tx = tid & 31, ty = tid >> 5;
#pragma unroll
    for (int i = 0; i < 4; ++i)
      tile[ty + i * 8][tx] = W[(size_t)(k0 + ty + i * 8) * 1024 + n0 + tx];
    __syncthreads();
#pragma unroll
    for (int i = 0; i < 4; ++i)
      WT[(size_t)(n0 + ty + i * 8) * 1024 + k0 + tx] = (f16)tile[tx][ty + i * 8];
  }
}

// ---------------- fused QKV+R GEMM: 128x128 tile, swizzled gload_lds, XCD swizzle ----
// 1D grid 896 = 8 XCD chunks x 112. id2<768: bsel=id2>>8 (Q/K/V); else R (M=2048).
// Within a matrix: consecutive id2 share m0 (A-panel) across the 8 n-blocks.
// LDS: physical 16B-chunk p of row r holds logical chunk p ^ (r&7).
__global__ __launch_bounds__(256) void gemm_qkvr(
    const f16* __restrict__ A, const f16* __restrict__ pb,
    const f16* __restrict__ Bq, const f16* __restrict__ Bk,
    const f16* __restrict__ Bv, const f16* __restrict__ Br,
    f16* __restrict__ Qw, f16* __restrict__ Qr,
    f16* __restrict__ Kb, f16* __restrict__ VTb, f16* __restrict__ Rb,
    const float* __restrict__ rw, const float* __restrict__ rr) {
  __shared__ f16 sm[17408];  // As[128*64] | Bs[128*64]; union with T[128][136]
  f16* As = sm;
  f16* Bs = sm + 8192;
  const int id2 = (blockIdx.x & 7) * 112 + (blockIdx.x >> 3);  // XCD-chunked
  int bsel, n0, m0;
  if (id2 < 768) {
    bsel = id2 >> 8;
    n0 = (id2 & 7) * 128;
    m0 = ((id2 & 255) >> 3) * 128;
  } else {
    bsel = 3;
    n0 = ((id2 - 768) & 7) * 128;
    m0 = ((id2 - 768) >> 3) * 128;
  }
  const f16* Ap = (bsel == 3) ? pb : A;
  const f16* Bw = bsel == 0 ? Bq : (bsel == 1 ? Bk : (bsel == 2 ? Bv : Br));
  const int tid = threadIdx.x, lane = tid & 63, wv = tid >> 6;
  const int wm = wv >> 1, wn = wv & 1, lg = lane >> 4, ln = lane & 15;
  const int srow = lane >> 3;                 // row within 8-row chunk
  const int sw = (lane & 7) ^ srow;           // pre-swizzled source 16B-chunk
  f32x4 acc[4][4] = {};

  for (int kt = 0; kt < 16; ++kt) {
    __syncthreads();
#pragma unroll
    for (int i = 0; i < 4; ++i) {
      int c = wv * 4 + i;  // 1KB chunk: rows 8c..8c+7
      gload16(Ap + (size_t)(m0 + c * 8 + srow) * 1024 + kt * 64 + sw * 8, &As[c * 512]);
      gload16(Bw + (size_t)(n0 + c * 8 + srow) * 1024 + kt * 64 + sw * 8, &Bs[c * 512]);
    }
    __syncthreads();
#pragma unroll
    for (int ks = 0; ks < 2; ++ks) {
      f16x8 af[4], bfr[4];
#pragma unroll
      for (int mi = 0; mi < 4; ++mi)
        af[mi] = *(const f16x8*)&As[(wm * 64 + mi * 16 + ln) * 64 +
                                    (((ks * 4 + lg) ^ (ln & 7)) * 8)];
#pragma unroll
      for (int ni = 0; ni < 4; ++ni)
        bfr[ni] = *(const f16x8*)&Bs[(wn * 64 + ni * 16 + ln) * 64 +
                                     (((ks * 4 + lg) ^ (ln & 7)) * 8)];
#pragma unroll
      for (int mi = 0; mi < 4; ++mi)
#pragma unroll
        for (int ni = 0; ni < 4; ++ni)
          acc[mi][ni] = __builtin_amdgcn_mfma_f32_16x16x32_f16(af[mi], bfr[ni],
                                                               acc[mi][ni], 0, 0, 0);
    }
  }

  if (bsel == 2) {  // V: transpose epilogue -> VT[b,n,d,s]
    __syncthreads();
    f16* T = sm;  // [128][136]
#pragma unroll
    for (int mi = 0; mi < 4; ++mi)
#pragma unroll
      for (int ni = 0; ni < 4; ++ni)
#pragma unroll
        for (int r = 0; r < 4; ++r) {
          int ml = wm * 64 + mi * 16 + 4 * lg + r;
          int cl = wn * 64 + ni * 16 + ln;
          T[cl * 136 + ml] = (f16)acc[mi][ni][r];
        }
    __syncthreads();
    int cl = tid >> 1, mb = (tid & 1) * 64;
    int gc = n0 + cl, gm = m0 + mb;
    int hh = gc >> 6, dd = gc & 63, bb = gm >> 11, ss = gm & 2047;
    f16* dst = VTb + ((size_t)(bb * 16 + hh) * 64 + dd) * 2048 + ss;
    const f16* srcT = &T[cl * 136 + mb];
#pragma unroll
    for (int i = 0; i < 8; ++i) *(f16x8*)&dst[i * 8] = *(const f16x8*)&srcT[i * 8];
  } else {
#pragma unroll
    for (int mi = 0; mi < 4; ++mi)
#pragma unroll
      for (int ni = 0; ni < 4; ++ni)
#pragma unroll
        for (int r = 0; r < 4; ++r) {
          int m = m0 + wm * 64 + mi * 16 + 4 * lg + r;
          int c = n0 + wn * 64 + ni * 16 + ln;
          float v = acc[mi][ni][r];
          size_t off = (size_t)m * 1024 + c;
          if (bsel == 0) {
            Qw[off] = (f16)(v + rw[c]);
            Qr[off] = (f16)(v + rr[c]);
          } else if (bsel == 1) {
            Kb[off] = (f16)v;
          } else {
            Rb[off] = (f16)v;
          }
        }
  }
}

// ---------------- BM=64 GEMM for O (+residual f32), XCD-chunked 1D grid 512 -------
__global__ __launch_bounds__(256) void gemm_o(
    const f16* __restrict__ A, const f16* __restrict__ Bw,
    float* __restrict__ fout, const float* __restrict__ xres) {
  __shared__ f16 As[4096];   // [64][64] swizzled
  __shared__ f16 Bs[8192];   // [128][64] swizzled
  const int id2 = (blockIdx.x & 7) * 64 + (blockIdx.x >> 3);
  const int n0 = (id2 & 7) * 128, m0 = (id2 >> 3) * 64;
  const int tid = threadIdx.x, lane = tid & 63, wv = tid >> 6;
  const int wm = wv >> 1, wn = wv & 1, lg = lane >> 4, ln = lane & 15;
  const int srow = lane >> 3;
  const int sw = (lane & 7) ^ srow;
  f32x4 acc[2][4] = {};

  for (int kt = 0; kt < 16; ++kt) {
    __syncthreads();
#pragma unroll
    for (int i = 0; i < 2; ++i) {
      int c = wv * 2 + i;
      gload16(A + (size_t)(m0 + c * 8 + srow) * 1024 + kt * 64 + sw * 8, &As[c * 512]);
    }
#pragma unroll
    for (int i = 0; i < 4; ++i) {
      int c = wv * 4 + i;
      gload16(Bw + (size_t)(n0 + c * 8 + srow) * 1024 + kt * 64 + sw * 8, &Bs[c * 512]);
    }
    __syncthreads();
#pragma unroll
    for (int ks = 0; ks < 2; ++ks) {
      f16x8 af[2], bfr[4];
#pragma unroll
      for (int mi = 0; mi < 2; ++mi)
        af[mi] = *(const f16x8*)&As[(wm * 32 + mi * 16 + ln) * 64 +
                                    (((ks * 4 + lg) ^ (ln & 7)) * 8)];
#pragma unroll
      for (int ni = 0; ni < 4; ++ni)
        bfr[ni] = *(const f16x8*)&Bs[(wn * 64 + ni * 16 + ln) * 64 +
                                     (((ks * 4 + lg) ^ (ln & 7)) * 8)];
#pragma unroll
      for (int mi = 0; mi < 2; ++mi)
#pragma unroll
        for (int ni = 0; ni < 4; ++ni)
          acc[mi][ni] = __builtin_amdgcn_mfma_f32_16x16x32_f16(af[mi], bfr[ni],
                                                               acc[mi][ni], 0, 0, 0);
    }
  }
#pragma unroll
  for (int mi = 0; mi < 2; ++mi)
#pragma unroll
    for (int ni = 0; ni < 4; ++ni)
#pragma unroll
      for (int r = 0; r < 4; ++r) {
        int m = m0 + wm * 32 + mi * 16 + 4 * lg + r;
        int c = n0 + wn * 64 + ni * 16 + ln;
        size_t off = (size_t)m * 1024 + c;
        fout[off] = acc[mi][ni][r] + xres[off];
      }
}

// chunk id c (0..79) -> (qt, ci). qt 0..7: 1 chunk; 8..15: 2; 16..23: 3; 24..31: 4.
__device__ __forceinline__ void chunk_map(int c, int& qt, int& ci) {
  if (c < 8) { qt = c; ci = 0; }
  else if (c < 24) { qt = 8 + ((c - 8) >> 1); ci = (c - 8) & 1; }
  else if (c < 48) { int d = c - 24; qt = 16 + d / 3; ci = d % 3; }
  else { int d = c - 48; qt = 24 + (d >> 2); ci = d & 3; }
}

// ---------------- split-K flash attention chunk kernel (R8 structure) ----------------
// QBLK=64, 4 waves; ring Rl slot j&127; descending-size dispatch (big chunks first).
__global__ __launch_bounds__(256) void attn_chunk(
    const f16* __restrict__ Qw, const f16* __restrict__ Qr,
    const f16* __restrict__ Kb, const f16* __restrict__ VT,
    const f16* __restrict__ Rb, f16* __restrict__ attb,
    f16* __restrict__ Opart, float* __restrict__ Mlp) {
  constexpr int LD = 72;
  constexpr int MW = 88;
  __shared__ f16 Kl[64 * LD];   // [key][d]
  __shared__ f16 Vl[64 * LD];   // [d][key]
  __shared__ f16 Rl[128 * LD];  // ring: slot j&127 holds r[j] (0 beyond 2047)
  __shared__ f16 Sl[64 * MW];   // wave-private union: M-park / P / out-bounce

  const int c = 79 - blockIdx.x;  // big chunks dispatch first
  int qt, ci;
  chunk_map(c, qt, ci);
  const int h = blockIdx.y, b = blockIdx.z;
  const int q0 = qt * 64;
  const int kts = ci * 8;
  const int kte = min(kts + 7, qt);
  const int tid = threadIdx.x, lane = tid & 63, wv = tid >> 6;
  const int lg = lane >> 4, ln = lane & 15;

  const size_t qoff = ((size_t)(b * 2048 + q0 + wv * 16 + ln) * 16 + h) * 64 + 8 * lg;
  f16x8 aqw[2], aqr[2];
  aqw[0] = *(const f16x8*)&Qw[qoff];
  aqw[1] = *(const f16x8*)&Qw[qoff + 32];
  aqr[0] = *(const f16x8*)&Qr[qoff];
  aqr[1] = *(const f16x8*)&Qr[qoff + 32];

  f32x4 oacc[4] = {};
  float mrun[4] = {-1e30f, -1e30f, -1e30f, -1e30f};
  float lrun[4] = {0.f, 0.f, 0.f, 0.f};

  const int r4 = tid >> 2, c16 = (tid & 3) * 16;  // K/V staging map (16B x2)
  const int t0 = 48 - 16 * wv;                    // wave-local BD window base

  f16x8 pk[2], pv[2], prn[2];  // prefetch registers
  auto load_kv = [&](int kt) {
    const int k0 = kt * 64;
    const f16* ksrc = Kb + ((size_t)(b * 2048 + k0 + r4) * 16 + h) * 64 + c16;
    pk[0] = *(const f16x8*)&ksrc[0];
    pk[1] = *(const f16x8*)&ksrc[8];
    const f16* vsrc = VT + ((size_t)(b * 16 + h) * 64 + r4) * 2048 + k0 + c16;
    pv[0] = *(const f16x8*)&vsrc[0];
    pv[1] = *(const f16x8*)&vsrc[8];
  };
  auto load_r = [&](int jbcur) {  // 64 new rows for next tile
    const int j = jbcur + 128 + r4;
    if (j < 2048) {
      const f16* rsrc = Rb + ((size_t)j * 16 + h) * 64 + c16;
      prn[0] = *(const f16x8*)&rsrc[0];
      prn[1] = *(const f16x8*)&rsrc[8];
    } else {
      f16x8 z = {};
      prn[0] = z;
      prn[1] = z;
    }
  };
  auto write_kv = [&]() {
    *(f16x8*)&Kl[r4 * LD + c16] = pk[0];
    *(f16x8*)&Kl[r4 * LD + c16 + 8] = pk[1];
    *(f16x8*)&Vl[r4 * LD + c16] = pv[0];
    *(f16x8*)&Vl[r4 * LD + c16 + 8] = pv[1];
  };
  auto write_r = [&](int jbcur) {
    const int slot = (jbcur + r4) & 127;  // (jb+128+r4)&127
    *(f16x8*)&Rl[slot * LD + c16] = prn[0];
    *(f16x8*)&Rl[slot * LD + c16 + 8] = prn[1];
  };

  const int jb0 = 1984 - q0 + kts * 64;
  load_kv(kts);
  write_kv();
  {
    const int r2 = tid >> 1, c32 = (tid & 1) * 32;
    const int j = jb0 + r2;
    const int slot = j & 127;
    if (j < 2048) {
      const f16* rsrc = Rb + ((size_t)j * 16 + h) * 64 + c32;
#pragma unroll
      for (int i = 0; i < 4; ++i)
        *(f16x8*)&Rl[slot * LD + c32 + i * 8] = *(const f16x8*)&rsrc[i * 8];
    } else {
      f16x8 z = {};
#pragma unroll
      for (int i = 0; i < 4; ++i) *(f16x8*)&Rl[slot * LD + c32 + i * 8] = z;
    }
  }
  __syncthreads();

  for (int kt = kts; kt <= kte; ++kt) {
    const int k0 = kt * 64;
    const int jb = 1984 - q0 + k0;
    if (kt < kte) {  // VMEM latency hides under compute below
      load_kv(kt + 1);
      load_r(jb);
    }

    // AC = (Q+rw) @ K^T
    f32x4 sc[4] = {};
#pragma unroll
    for (int ks = 0; ks < 2; ++ks)
#pragma unroll
      for (int ni = 0; ni < 4; ++ni) {
        f16x8 kf = *(const f16x8*)&Kl[(ni * 16 + ln) * LD + ks * 32 + 8 * lg];
        sc[ni] = __builtin_amdgcn_mfma_f32_16x16x32_f16(aqw[ks], kf, sc[ni], 0, 0, 0);
      }

    // BD wave-local 80-wide window via ring slots
    f32x4 mw[5] = {};
#pragma unroll
    for (int ks = 0; ks < 2; ++ks)
#pragma unroll
      for (int nj = 0; nj < 5; ++nj) {
        const int slot = (jb + t0 + nj * 16 + ln) & 127;
        f16x8 rf = *(const f16x8*)&Rl[slot * LD + ks * 32 + 8 * lg];
        mw[nj] = __builtin_amdgcn_mfma_f32_16x16x32_f16(aqr[ks], rf, mw[nj], 0, 0, 0);
      }

    // park M (wave-private rows), shear-gather BD[ql,ki] = M[ql, ki-ql+15]
#pragma unroll
    for (int nj = 0; nj < 5; ++nj)
#pragma unroll
      for (int r = 0; r < 4; ++r)
        Sl[(wv * 16 + 4 * lg + r) * MW + nj * 16 + ln] = (f16)mw[nj][r];

#pragma unroll
    for (int ni = 0; ni < 4; ++ni)
#pragma unroll
      for (int r = 0; r < 4; ++r) {
        int ql = 4 * lg + r;
        int ki = ni * 16 + ln;
        float bd = (float)Sl[(wv * 16 + ql) * MW + ki - ql + 15];
        float s = (sc[ni][r] + bd) * 0.125f;
        if (k0 + ki > q0 + wv * 16 + ql) s = -1e30f;  // strict causal (diag tile)
        sc[ni][r] = s;
      }

    // online softmax over 16-lane row groups
#pragma unroll
    for (int r = 0; r < 4; ++r) {
      float mx = sc[0][r];
#pragma unroll
      for (int ni = 1; ni < 4; ++ni) mx = fmaxf(mx, sc[ni][r]);
#pragma unroll
      for (int off = 1; off < 16; off <<= 1) mx = fmaxf(mx, __shfl_xor(mx, off, 16));
      float mnew = fmaxf(mrun[r], mx);
      float corr = __expf(mrun[r] - mnew);
      mrun[r] = mnew;
      float rs = 0.f;
#pragma unroll
      for (int ni = 0; ni < 4; ++ni) {
        float p = __expf(sc[ni][r] - mnew);
        sc[ni][r] = p;
        rs += p;
      }
#pragma unroll
      for (int off = 1; off < 16; off <<= 1) rs += __shfl_xor(rs, off, 16);
      lrun[r] = lrun[r] * corr + rs;
#pragma unroll
      for (int ni = 0; ni < 4; ++ni) oacc[ni][r] *= corr;
    }

    // P park (wave-private rows), PV from Vl
#pragma unroll
    for (int ni = 0; ni < 4; ++ni)
#pragma unroll
      for (int r = 0; r < 4; ++r)
        Sl[(wv * 16 + 4 * lg + r) * MW + ni * 16 + ln] = (f16)sc[ni][r];

#pragma unroll
    for (int ks = 0; ks < 2; ++ks) {
      f16x8 pf = *(const f16x8*)&Sl[(wv * 16 + ln) * MW + ks * 32 + 8 * lg];
#pragma unroll
      for (int ni = 0; ni < 4; ++ni) {
        f16x8 vf = *(const f16x8*)&Vl[(ni * 16 + ln) * LD + ks * 32 + 8 * lg];
        oacc[ni] = __builtin_amdgcn_mfma_f32_16x16x32_f16(pf, vf, oacc[ni], 0, 0, 0);
      }
    }

    __syncthreads();  // all waves done reading LDS of this tile
    if (kt < kte) {
      write_kv();
      write_r(jb);
      __syncthreads();
    }
  }

  if (qt < 8) {
    // single chunk: normalize, bounce via wave-private rows, store final
#pragma unroll
    for (int ni = 0; ni < 4; ++ni)
#pragma unroll
      for (int r = 0; r < 4; ++r)
        Sl[(wv * 16 + 4 * lg + r) * MW + ni * 16 + ln] = (f16)(oacc[ni][r] / lrun[r]);
#pragma unroll
    for (int i = 0; i < 2; ++i) {
      int row = wv * 16 + i * 8 + (lane >> 3);
      int col = (lane & 7) * 8;
      *(f16x8*)&attb[((size_t)(b * 2048 + q0 + row) * 16 + h) * 64 + col] =
          *(const f16x8*)&Sl[row * MW + col];
    }
  } else {
    const size_t pidx = (size_t)(b * 16 + h) * 80 + c;
    // unnormalized O~ partial via wave-private bounce
#pragma unroll
    for (int ni = 0; ni < 4; ++ni)
#pragma unroll
      for (int r = 0; r < 4; ++r)
        Sl[(wv * 16 + 4 * lg + r) * MW + ni * 16 + ln] = (f16)oacc[ni][r];
    if (ln == 0) {
#pragma unroll
      for (int r = 0; r < 4; ++r) {
        int row = wv * 16 + 4 * lg + r;
        Mlp[pidx * 128 + row] = mrun[r];
        Mlp[pidx * 128 + 64 + row] = lrun[r];
      }
    }
#pragma unroll
    for (int i = 0; i < 2; ++i) {
      int row = wv * 16 + i * 8 + (lane >> 3);
      int col = (lane & 7) * 8;
      *(f16x8*)&Opart[pidx * 4096 + row * 64 + col] = *(const f16x8*)&Sl[row * MW + col];
    }
  }
}

// ---------------- combine partials for qt >= 8 ----------------
__global__ __launch_bounds__(256) void combine_kernel(
    const f16* __restrict__ Opart, const float* __restrict__ Mlp,
    f16* __restrict__ attb) {
  const int qt = 8 + blockIdx.x, h = blockIdx.y, b = blockIdx.z;
  const int nc = (qt + 8) >> 3;  // ceil((qt+1)/8), 2..4
  int cbase;
  if (qt < 16) cbase = 8 + 2 * (qt - 8);
  else if (qt < 24) cbase = 24 + 3 * (qt - 16);
  else cbase = 48 + 4 * (qt - 24);
  const int tid = threadIdx.x;
  const int row = tid >> 2, d0 = (tid & 3) * 16;
  const size_t pbase = (size_t)(b * 16 + h) * 80 + cbase;

  float m[4], l[4], w[4];
  float M = -1e30f;
#pragma unroll
  for (int i = 0; i < 4; ++i)
    if (i < nc) {
      m[i] = Mlp[(pbase + i) * 128 + row];
      l[i] = Mlp[(pbase + i) * 128 + 64 + row];
      M = fmaxf(M, m[i]);
    }
  float wsum = 0.f;
#pragma unroll
  for (int i = 0; i < 4; ++i)
    if (i < nc) {
      w[i] = __expf(m[i] - M);
      wsum += w[i] * l[i];
    }
  float o[16] = {};
#pragma unroll
  for (int i = 0; i < 4; ++i)
    if (i < nc) {
      const f16* src = &Opart[(pbase + i) * 4096 + row * 64 + d0];
      f16x8 v0 = *(const f16x8*)&src[0];
      f16x8 v1 = *(const f16x8*)&src[8];
#pragma unroll
      for (int j = 0; j < 8; ++j) {
        o[j] += w[i] * (float)v0[j];
        o[8 + j] += w[i] * (float)v1[j];
      }
    }
  float inv = 1.f / wsum;
  f16x8 r0, r1;
#pragma unroll
  for (int j = 0; j < 8; ++j) {
    r0[j] = (f16)(o[j] * inv);
    r1[j] = (f16)(o[8 + j] * inv);
  }
  f16* dst = &attb[((size_t)(b * 2048 + qt * 64 + row) * 16 + h) * 64 + d0];
  *(f16x8*)&dst[0] = r0;
  *(f16x8*)&dst[8] = r1;
}

// ---------------- LayerNorm over last dim (1024), f32 out ----------------
__global__ __launch_bounds__(256) void ln_kernel(const float* __restrict__ pre,
                                                 const float* __restrict__ gamma,
                                                 const float* __restrict__ beta,
                                                 float* __restrict__ out) {
  __shared__ float red[8];
  const int row = blockIdx.x, t = threadIdx.x;
  f32x4 v = *(const f32x4*)&pre[(size_t)row * 1024 + t * 4];
  float s = v[0] + v[1] + v[2] + v[3];
  float s2 = v[0] * v[0] + v[1] * v[1] + v[2] * v[2] + v[3] * v[3];
#pragma unroll
  for (int off = 1; off < 64; off <<= 1) {
    s += __shfl_xor(s, off, 64);
    s2 += __shfl_xor(s2, off, 64);
  }
  if ((t & 63) == 0) {
    red[t >> 6] = s;
    red[(t >> 6) + 4] = s2;
  }
  __syncthreads();
  s = red[0] + red[1] + red[2] + red[3];
  s2 = red[4] + red[5] + red[6] + red[7];
  float mean = s * (1.f / 1024.f);
  float var = s2 * (1.f / 1024.f) - mean * mean;
  float rcp = rsqrtf(var + 1e-5f);
  f32x4 g = *(const f32x4*)&gamma[t * 4];
  f32x4 be = *(const f32x4*)&beta[t * 4];
  f32x4 o;
#pragma unroll
  for (int j = 0; j < 4; ++j) o[j] = (v[j] - mean) * rcp * g[j] + be[j];
  *(f32x4*)&out[(size_t)row * 1024 + t * 4] = o;
}

extern "C" void kernel_launch(void* const* d_in, const int* in_sizes, int n_in,
                              void* d_out, int out_size, void* d_ws, size_t ws_size,
                              hipStream_t stream) {
  const float* x = (const float*)d_in[0];
  const float* pe = (const float*)d_in[2];
  const float* rr = (const float*)d_in[3];
  const float* rw = (const float*)d_in[4];
  const float* Wq = (const float*)d_in[5];
  const float* Wk = (const float*)d_in[6];
  const float* Wv = (const float*)d_in[7];
  const float* Wr = (const float*)d_in[8];
  const float* Wo = (const float*)d_in[9];
  const float* gamma = (const float*)d_in[10];
  const float* beta = (const float*)d_in[11];
  float* out = (float*)d_out;

  char* w = (char*)d_ws;
  auto alloc = [&](size_t bytes) {
    char* p = w;
    w += (bytes + 255) & ~(size_t)255;
    return p;
  };
  float* preln = (float*)alloc(4096ull * 1024 * 4);
  f16* xb = (f16*)alloc(4096ull * 1024 * 2);
  f16* pb = (f16*)alloc(2048ull * 1024 * 2);
  f16* WTq = (f16*)alloc(1024ull * 1024 * 2);
  f16* WTk = (f16*)alloc(1024ull * 1024 * 2);
  f16* WTv = (f16*)alloc(1024ull * 1024 * 2);
  f16* WTr = (f16*)alloc(1024ull * 1024 * 2);
  f16* WTo = (f16*)alloc(1024ull * 1024 * 2);
  f16* Qw = (f16*)alloc(4096ull * 1024 * 2);
  f16* Qr = (f16*)alloc(4096ull * 1024 * 2);
  f16* Kb = (f16*)alloc(4096ull * 1024 * 2);
  f16* VTb = (f16*)alloc(4096ull * 1024 * 2);
  f16* Rb = (f16*)alloc(2048ull * 1024 * 2);
  f16* attb = (f16*)alloc(4096ull * 1024 * 2);
  f16* Opart = (f16*)alloc(2ull * 16 * 80 * 4096 * 2);  // 21 MB unnormalized O~
  float* Mlp = (float*)alloc(2ull * 16 * 80 * 128 * 4); // 1.3 MB m/l

  prep_kernel<<<11264, 256, 0, stream>>>(x, xb, pe, pb, Wq, Wk, Wv, Wr, Wo,
                                         WTq, WTk, WTv, WTr, WTo);

  gemm_qkvr<<<896, 256, 0, stream>>>(xb, pb, WTq, WTk, WTv, WTr,
                                     Qw, Qr, Kb, VTb, Rb, rw, rr);

  attn_chunk<<<dim3(80, 16, 2), 256, 0, stream>>>(Qw, Qr, Kb, VTb, Rb, attb, Opart, Mlp);
  combine_kernel<<<dim3(24, 16, 2), 256, 0, stream>>>(Opart, Mlp, attb);

  gemm_o<<<512, 256, 0, stream>>>(attb, WTo, preln, x);
  ln_kernel<<<4096, 256, 0, stream>>>(preln, gamma, beta, out);
}